// Round 10
// baseline (214.258 us; speedup 1.0000x reference)
//
#include <hip/hip_runtime.h>

// Batched 8x8 iDCT: out = M^T * img * M + 128
//   M[i][j] = 0.5 * a[i] * cos((2j+1)*i*pi/16)
//   a[i]    = alpha[i*8+1]       (alpha = outer(a,a), a[1]==1)
//   cos term = dct[i*512 + j*8]  (dct_tensor[i,0,j,0]; cos(0)==1)
//
// Design J: persistent resident grid + 1-deep prefetch + barrier-free exchange.
//   - 1024 WGs = exactly 4 resident per CU (LDS 34.8KB x4 = 139KB < 160KB,
//     lb(256,4) = 4 waves/SIMD): zero WG churn, each WG loops ~16 tiles
//   - next tile's 8 dwordx4 issued BEFORE current tile's compute -> reads in
//     flight through compute+exchange+store; steady state = free-running stream
//   - lb(256,4) gives 128 VGPRs: cur 32 + nxt 32 + temps ~35 fits WITHOUT the
//     spill that killed R6/R8 (their (256,8) 64-VGPR cap -> scratch traffic)
//   - P-exchange intra-wave (lane t writes block t>>3, same 8 lanes read) ->
//     no __syncthreads, only wave-local s_waitcnt lgkmcnt(0) (R8/R9 proven)
//   - LDS stride 17 float4/block: 2-lane/bank (free) writes, broadcast reads
//   - plain stores (NT proven harmful in R6)

#define WG      256
#define SETS    4
#define BLKWG   128                   // blocks per tile (4 waves x 32)
#define STRIDE4 17                    // float4 stride per block slot in LDS
#define NWG     1024                  // 4 resident WGs per CU x 256 CUs

__global__ __launch_bounds__(WG, 4) void dct8x8_kernel(
    const float* __restrict__ image,
    const float* __restrict__ alpha,
    const float* __restrict__ dct,
    float* __restrict__ out,
    int nblocks)
{
    __shared__ float4 lds4[BLKWG * STRIDE4];   // 34816 B

    const int t = threadIdx.x;
    const int w = t >> 6;              // wave 0..3
    const int lane = t & 63;
    const int b8 = lane >> 3;          // block-within-set 0..7
    const int r = lane & 7;            // my row
    const int myoff = w * 512 + b8 * 16 + r * 2;   // float4 offset within tile

    const float4* __restrict__ in4 = (const float4*)image;
    float4* __restrict__ o4 = (float4*)out;
    const long long ntiles = ((long long)nblocks + BLKWG - 1) / BLKWG;

    long long tile = blockIdx.x;
    if (tile >= ntiles) return;

    // ---- prologue: load tile0 (8 dwordx4 in flight) ----
    float4 c[2 * SETS];
    {
        const long long gb = tile * BLKWG;
        const bool full = gb + BLKWG <= (long long)nblocks;
#pragma unroll
        for (int s = 0; s < SETS; ++s) {
            const long long g = gb + w * 32 + s * 8 + b8;
            if (full || g < nblocks) {
                const size_t p = (size_t)tile * 2048 + myoff + s * 128;
                c[2 * s] = in4[p]; c[2 * s + 1] = in4[p + 1];
            } else {
                c[2 * s] = make_float4(0.f, 0.f, 0.f, 0.f);
                c[2 * s + 1] = c[2 * s];
            }
        }
    }

    // ---- M -> SGPRs via readlane (overlaps load latency) ----
    float mv;
    {
        const int i = lane >> 3, j = lane & 7;
        mv = 0.5f * alpha[i * 8 + 1] * dct[i * 512 + j * 8];
    }
    float M[64];
#pragma unroll
    for (int k = 0; k < 64; ++k)
        M[k] = __int_as_float(__builtin_amdgcn_readlane(__float_as_int(mv), k));

    // stage-2 weights M[x][r] (runtime r): per-lane loads, cache-hot
    float mu[8];
#pragma unroll
    for (int x = 0; x < 8; ++x)
        mu[x] = 0.5f * alpha[x * 8 + 1] * dct[x * 512 + r * 8];

    while (true) {
        // ---- prefetch next tile (in flight through compute + store) ----
        const long long nxt = tile + gridDim.x;
        const bool have = nxt < ntiles;
        float4 n_[2 * SETS];
        if (have) {
            const long long gb = nxt * BLKWG;
            const bool full = gb + BLKWG <= (long long)nblocks;
#pragma unroll
            for (int s = 0; s < SETS; ++s) {
                const long long g = gb + w * 32 + s * 8 + b8;
                if (full || g < nblocks) {
                    const size_t p = (size_t)nxt * 2048 + myoff + s * 128;
                    n_[2 * s] = in4[p]; n_[2 * s + 1] = in4[p + 1];
                } else {
                    n_[2 * s] = make_float4(0.f, 0.f, 0.f, 0.f);
                    n_[2 * s + 1] = n_[2 * s];
                }
            }
        }

        // ---- stage 1 per set: P[v] = sum_y row[y]*M[y][v] -> LDS ----
#pragma unroll
        for (int s = 0; s < SETS; ++s) {
            const float row[8] = {c[2*s].x, c[2*s].y, c[2*s].z, c[2*s].w,
                                  c[2*s+1].x, c[2*s+1].y, c[2*s+1].z, c[2*s+1].w};
            float P[8];
#pragma unroll
            for (int v = 0; v < 8; ++v) {
                float acc = 0.0f;
#pragma unroll
                for (int y = 0; y < 8; ++y)
                    acc = fmaf(row[y], M[y * 8 + v], acc);
                P[v] = acc;
            }
            float4* buf = &lds4[(w * 32 + s * 8 + b8) * STRIDE4];
            buf[r * 2 + 0] = make_float4(P[0], P[1], P[2], P[3]);
            buf[r * 2 + 1] = make_float4(P[4], P[5], P[6], P[7]);
        }

        // wave-local: my ds_writes commit in order; exchange is intra-wave
        asm volatile("s_waitcnt lgkmcnt(0)" ::: "memory");

        // ---- stage 2 per set: O[v] = 128 + sum_x mu[x]*P[x][v]; store ----
        {
            const long long gb = tile * BLKWG;
            const bool full = gb + BLKWG <= (long long)nblocks;
#pragma unroll
            for (int s = 0; s < SETS; ++s) {
                const float4* buf = &lds4[(w * 32 + s * 8 + b8) * STRIDE4];
                float O[8] = {128.f,128.f,128.f,128.f,128.f,128.f,128.f,128.f};
#pragma unroll
                for (int x = 0; x < 8; ++x) {
                    const float4 plo = buf[x * 2 + 0];
                    const float4 phi = buf[x * 2 + 1];
                    const float m = mu[x];
                    O[0] = fmaf(m, plo.x, O[0]);
                    O[1] = fmaf(m, plo.y, O[1]);
                    O[2] = fmaf(m, plo.z, O[2]);
                    O[3] = fmaf(m, plo.w, O[3]);
                    O[4] = fmaf(m, phi.x, O[4]);
                    O[5] = fmaf(m, phi.y, O[5]);
                    O[6] = fmaf(m, phi.z, O[6]);
                    O[7] = fmaf(m, phi.w, O[7]);
                }
                const long long g = gb + w * 32 + s * 8 + b8;
                if (full || g < nblocks) {
                    const size_t p = (size_t)tile * 2048 + myoff + s * 128;
                    o4[p]     = make_float4(O[0], O[1], O[2], O[3]);
                    o4[p + 1] = make_float4(O[4], O[5], O[6], O[7]);
                }
            }
        }

        // keep next iter's ds_writes after this iter's ds_reads (HW: per-wave
        // DS ordering; compiler: alias + this fence)
        asm volatile("" ::: "memory");

        if (!have) break;
#pragma unroll
        for (int k = 0; k < 2 * SETS; ++k) c[k] = n_[k];
        tile = nxt;
    }
}

extern "C" void kernel_launch(void* const* d_in, const int* in_sizes, int n_in,
                              void* d_out, int out_size, void* d_ws, size_t ws_size,
                              hipStream_t stream) {
    const float* image = (const float*)d_in[0];
    const float* alpha = (const float*)d_in[1];
    const float* dct   = (const float*)d_in[2];
    float* outp = (float*)d_out;

    const int nblocks = in_sizes[0] / 64;
    const long long ntiles = ((long long)nblocks + BLKWG - 1) / BLKWG;
    int grid = (int)((ntiles < NWG) ? ntiles : NWG);
    if (grid < 1) grid = 1;

    dct8x8_kernel<<<grid, WG, 0, stream>>>(image, alpha, dct, outp, nblocks);
}

// Round 11
// 206.763 us; speedup vs baseline: 1.0363x; 1.0363x over previous
//
#include <hip/hip_runtime.h>

// Batched 8x8 iDCT: out = M^T * img * M + 128
//   M[i][j] = 0.5 * a[i] * cos((2j+1)*i*pi/16)
//   a[i]    = alpha[i*8+1]       (alpha = outer(a,a), a[1]==1)
//   cos term = dct[i*512 + j*8]  (dct_tensor[i,0,j,0]; cos(0)==1)
//
// Design K: max-residency barrier-free row-per-lane.
//   - SETS=2 -> LDS 17.4KB/WG -> 8 WGs/CU resident (32 waves/CU, 2x Design I)
//     lb(256,8): body proven to fit 32 VGPR with no spill (R7), unlike the
//     prefetch variants (R6/R8) whose extra float4 state spilled at this cap
//   - lane owns one row of each of its 2 blocks; all global ops dwordx4,
//     lanes stride 32B -> fully coalesced; wave covers 4KB in / 4KB out
//   - P-exchange intra-wave (lane t writes block t>>3, same 8 lanes read) ->
//     no __syncthreads, only wave-local s_waitcnt lgkmcnt(0) (R8/R9 proven)
//   - LDS stride 17 float4/block: conflict-free writes, broadcast reads
//   - N_BLOCKS % 64 == 0 -> guard-free FULL path (template)
//   - plain stores (NT proven harmful R6); one-shot WGs (persistence null R10)

#define WG      256
#define SETS    2
#define BLKWG   64                    // blocks per WG (4 waves x 16)
#define STRIDE4 17                    // float4 stride per block slot in LDS

template<bool FULL>
__device__ __forceinline__ void process_tile(
    const float4* __restrict__ in4, float4* __restrict__ o4,
    float4* __restrict__ lds4, const float* __restrict__ alpha,
    const float* __restrict__ dct, long long wgbase, int nblocks,
    int w, int b8, int r, int lane)
{
    const long long myblk0 = wgbase + w * (SETS * 8) + b8;   // + s*8 per set

    // ---- issue ALL loads first (4 dwordx4 in flight per lane) ----
    float4 lo[SETS], hi[SETS];
#pragma unroll
    for (int s = 0; s < SETS; ++s) {
        const long long g = myblk0 + s * 8;
        if (FULL || g < nblocks) {
            const size_t p = (size_t)g * 16 + r * 2;
            lo[s] = in4[p];
            hi[s] = in4[p + 1];
        } else {
            lo[s] = make_float4(0.f, 0.f, 0.f, 0.f);
            hi[s] = lo[s];
        }
    }

    // ---- M -> SGPRs via readlane (overlaps the load latency) ----
    float mv;
    {
        const int i = lane >> 3, j = lane & 7;
        mv = 0.5f * alpha[i * 8 + 1] * dct[i * 512 + j * 8];
    }
    float M[64];
#pragma unroll
    for (int k = 0; k < 64; ++k)
        M[k] = __int_as_float(__builtin_amdgcn_readlane(__float_as_int(mv), k));

    // stage-2 weights M[x][r] (runtime r): per-lane loads, cache-hot
    float mu[8];
#pragma unroll
    for (int x = 0; x < 8; ++x)
        mu[x] = 0.5f * alpha[x * 8 + 1] * dct[x * 512 + r * 8];

    // ---- stage 1 per set: P[v] = sum_y row[y]*M[y][v] -> LDS slot ----
#pragma unroll
    for (int s = 0; s < SETS; ++s) {
        const float row[8] = {lo[s].x, lo[s].y, lo[s].z, lo[s].w,
                              hi[s].x, hi[s].y, hi[s].z, hi[s].w};
        float P[8];
#pragma unroll
        for (int v = 0; v < 8; ++v) {
            float acc = 0.0f;
#pragma unroll
            for (int y = 0; y < 8; ++y)
                acc = fmaf(row[y], M[y * 8 + v], acc);
            P[v] = acc;
        }
        float4* buf = &lds4[(w * (SETS * 8) + s * 8 + b8) * STRIDE4];
        buf[r * 2 + 0] = make_float4(P[0], P[1], P[2], P[3]);
        buf[r * 2 + 1] = make_float4(P[4], P[5], P[6], P[7]);
    }

    // wave-local: my wave's ds_writes commit in order; exchange is intra-wave
    asm volatile("s_waitcnt lgkmcnt(0)" ::: "memory");

    // ---- stage 2 per set: O[v] = 128 + sum_x mu[x]*P[x][v]; store row ----
#pragma unroll
    for (int s = 0; s < SETS; ++s) {
        const float4* buf = &lds4[(w * (SETS * 8) + s * 8 + b8) * STRIDE4];
        float O[8] = {128.f, 128.f, 128.f, 128.f, 128.f, 128.f, 128.f, 128.f};
#pragma unroll
        for (int x = 0; x < 8; ++x) {
            const float4 plo = buf[x * 2 + 0];
            const float4 phi = buf[x * 2 + 1];
            const float m = mu[x];
            O[0] = fmaf(m, plo.x, O[0]);
            O[1] = fmaf(m, plo.y, O[1]);
            O[2] = fmaf(m, plo.z, O[2]);
            O[3] = fmaf(m, plo.w, O[3]);
            O[4] = fmaf(m, phi.x, O[4]);
            O[5] = fmaf(m, phi.y, O[5]);
            O[6] = fmaf(m, phi.z, O[6]);
            O[7] = fmaf(m, phi.w, O[7]);
        }
        const long long g = myblk0 + s * 8;
        if (FULL || g < nblocks) {
            const size_t p = (size_t)g * 16 + r * 2;
            o4[p]     = make_float4(O[0], O[1], O[2], O[3]);
            o4[p + 1] = make_float4(O[4], O[5], O[6], O[7]);
        }
    }
}

__global__ __launch_bounds__(WG, 8) void dct8x8_kernel(
    const float* __restrict__ image,
    const float* __restrict__ alpha,
    const float* __restrict__ dct,
    float* __restrict__ out,
    int nblocks)
{
    __shared__ float4 lds4[BLKWG * STRIDE4];   // 64*17*16B = 17408B

    const int t = threadIdx.x;
    const int w = t >> 6;          // wave 0..3
    const int lane = t & 63;
    const int b8 = lane >> 3;      // block-within-wave-set 0..7
    const int r = lane & 7;        // my row

    const long long wgbase = (long long)blockIdx.x * BLKWG;
    const float4* in4 = (const float4*)image;
    float4* o4 = (float4*)out;

    if (wgbase + BLKWG <= (long long)nblocks) {
        process_tile<true >(in4, o4, lds4, alpha, dct, wgbase, nblocks, w, b8, r, lane);
    } else {
        process_tile<false>(in4, o4, lds4, alpha, dct, wgbase, nblocks, w, b8, r, lane);
    }
}

extern "C" void kernel_launch(void* const* d_in, const int* in_sizes, int n_in,
                              void* d_out, int out_size, void* d_ws, size_t ws_size,
                              hipStream_t stream) {
    const float* image = (const float*)d_in[0];
    const float* alpha = (const float*)d_in[1];
    const float* dct   = (const float*)d_in[2];
    float* outp = (float*)d_out;

    const int nblocks = in_sizes[0] / 64;
    const long long wgs = ((long long)nblocks + BLKWG - 1) / BLKWG;

    dct8x8_kernel<<<(int)wgs, WG, 0, stream>>>(image, alpha, dct, outp, nblocks);
}

// Round 12
// 204.623 us; speedup vs baseline: 1.0471x; 1.0105x over previous
//
#include <hip/hip_runtime.h>

// Batched 8x8 iDCT: out = M^T * img * M + 128
//   M[i][j] = 0.5 * a[i] * cos((2j+1)*i*pi/16)
//   a[i]    = alpha[i*8+1]       (alpha = outer(a,a), a[1]==1)
//   cos term = dct[i*512 + j*8]  (dct_tensor[i,0,j,0]; cos(0)==1)
//
// Design L: R9 winner + non-temporal stores (clean isolation).
//   - row-per-lane, 4 blocks/thread, all 8 dwordx4 loads issued up front
//   - lb(256,4): 128 VGPRs -> no spill (R6/R8's NT/prefetch tests were
//     confounded by spill at the 64-VGPR lb(256,8) cap; this isolates NT)
//   - barrier-free intra-wave P-exchange (R8/R9/R11 proven): wave-local
//     s_waitcnt lgkmcnt(0) only
//   - LDS stride 17 float4/block: conflict-free writes, broadcast reads
//   - NT stores: output is write-once; early-evict keeps more of the 512MB
//     input resident in the 256MB L3 across graph replays -> FETCH drops

#define WG      256
#define SETS    4
#define BLKWAVE 32                    // blocks per wave (SETS * 8)
#define BLKWG   128                   // blocks per WG (4 waves)
#define STRIDE4 17                    // float4 stride per block slot in LDS

typedef float fx4 __attribute__((ext_vector_type(4)));

template<bool FULL>
__device__ __forceinline__ void process_tile(
    const float4* __restrict__ in4, float* __restrict__ outp,
    float4* __restrict__ lds4, const float* __restrict__ alpha,
    const float* __restrict__ dct, long long wgbase, int nblocks,
    int w, int b8, int r, int lane)
{
    const long long myblk0 = wgbase + w * BLKWAVE + b8;   // + s*8 per set

    // ---- issue ALL loads first (8 dwordx4 in flight per lane) ----
    float4 lo[SETS], hi[SETS];
#pragma unroll
    for (int s = 0; s < SETS; ++s) {
        const long long g = myblk0 + s * 8;
        if (FULL || g < nblocks) {
            const size_t p = (size_t)g * 16 + r * 2;
            lo[s] = in4[p];
            hi[s] = in4[p + 1];
        } else {
            lo[s] = make_float4(0.f, 0.f, 0.f, 0.f);
            hi[s] = lo[s];
        }
    }

    // ---- M -> SGPRs via readlane (overlaps the load latency) ----
    float mv;
    {
        const int i = lane >> 3, j = lane & 7;
        mv = 0.5f * alpha[i * 8 + 1] * dct[i * 512 + j * 8];
    }
    float M[64];
#pragma unroll
    for (int k = 0; k < 64; ++k)
        M[k] = __int_as_float(__builtin_amdgcn_readlane(__float_as_int(mv), k));

    // stage-2 weights M[x][r] (runtime r): per-lane loads, cache-hot
    float mu[8];
#pragma unroll
    for (int x = 0; x < 8; ++x)
        mu[x] = 0.5f * alpha[x * 8 + 1] * dct[x * 512 + r * 8];

    // ---- stage 1 per set: P[v] = sum_y row[y]*M[y][v] -> LDS slot ----
#pragma unroll
    for (int s = 0; s < SETS; ++s) {
        const float row[8] = {lo[s].x, lo[s].y, lo[s].z, lo[s].w,
                              hi[s].x, hi[s].y, hi[s].z, hi[s].w};
        float P[8];
#pragma unroll
        for (int v = 0; v < 8; ++v) {
            float acc = 0.0f;
#pragma unroll
            for (int y = 0; y < 8; ++y)
                acc = fmaf(row[y], M[y * 8 + v], acc);
            P[v] = acc;
        }
        float4* buf = &lds4[(w * BLKWAVE + s * 8 + b8) * STRIDE4];
        buf[r * 2 + 0] = make_float4(P[0], P[1], P[2], P[3]);
        buf[r * 2 + 1] = make_float4(P[4], P[5], P[6], P[7]);
    }

    // wave-local: my wave's ds_writes commit in order; exchange is intra-wave
    asm volatile("s_waitcnt lgkmcnt(0)" ::: "memory");

    // ---- stage 2 per set: O[v] = 128 + sum_x mu[x]*P[x][v]; NT-store row ----
#pragma unroll
    for (int s = 0; s < SETS; ++s) {
        const float4* buf = &lds4[(w * BLKWAVE + s * 8 + b8) * STRIDE4];
        float O[8] = {128.f, 128.f, 128.f, 128.f, 128.f, 128.f, 128.f, 128.f};
#pragma unroll
        for (int x = 0; x < 8; ++x) {
            const float4 plo = buf[x * 2 + 0];
            const float4 phi = buf[x * 2 + 1];
            const float m = mu[x];
            O[0] = fmaf(m, plo.x, O[0]);
            O[1] = fmaf(m, plo.y, O[1]);
            O[2] = fmaf(m, plo.z, O[2]);
            O[3] = fmaf(m, plo.w, O[3]);
            O[4] = fmaf(m, phi.x, O[4]);
            O[5] = fmaf(m, phi.y, O[5]);
            O[6] = fmaf(m, phi.z, O[6]);
            O[7] = fmaf(m, phi.w, O[7]);
        }
        const long long g = myblk0 + s * 8;
        if (FULL || g < nblocks) {
            fx4* p = (fx4*)(outp + ((size_t)g * 64 + (size_t)r * 8));
            fx4 v0 = {O[0], O[1], O[2], O[3]};
            fx4 v1 = {O[4], O[5], O[6], O[7]};
            __builtin_nontemporal_store(v0, p);
            __builtin_nontemporal_store(v1, p + 1);
        }
    }
}

__global__ __launch_bounds__(WG, 4) void dct8x8_kernel(
    const float* __restrict__ image,
    const float* __restrict__ alpha,
    const float* __restrict__ dct,
    float* __restrict__ out,
    int nblocks)
{
    __shared__ float4 lds4[BLKWG * STRIDE4];   // 128*17*16B = 34816B

    const int t = threadIdx.x;
    const int w = t >> 6;          // wave 0..3
    const int lane = t & 63;
    const int b8 = lane >> 3;      // block-within-wave-set 0..7
    const int r = lane & 7;        // my row

    const long long wgbase = (long long)blockIdx.x * BLKWG;
    const float4* in4 = (const float4*)image;

    if (wgbase + BLKWG <= (long long)nblocks) {
        process_tile<true >(in4, out, lds4, alpha, dct, wgbase, nblocks, w, b8, r, lane);
    } else {
        process_tile<false>(in4, out, lds4, alpha, dct, wgbase, nblocks, w, b8, r, lane);
    }
}

extern "C" void kernel_launch(void* const* d_in, const int* in_sizes, int n_in,
                              void* d_out, int out_size, void* d_ws, size_t ws_size,
                              hipStream_t stream) {
    const float* image = (const float*)d_in[0];
    const float* alpha = (const float*)d_in[1];
    const float* dct   = (const float*)d_in[2];
    float* outp = (float*)d_out;

    const int nblocks = in_sizes[0] / 64;
    const long long wgs = ((long long)nblocks + BLKWG - 1) / BLKWG;

    dct8x8_kernel<<<(int)wgs, WG, 0, stream>>>(image, alpha, dct, outp, nblocks);
}